// Round 1
// 529.329 us; speedup vs baseline: 1.1358x; 1.1358x over previous
//
#include <hip/hip_runtime.h>

// Problem constants
#define M_TOT 8192      // 4 * 2048
#define K_TOT 4096      // IN_FEATURES
#define N_TOT 4096      // OUT_FEATURES
#define RANK  64
#define SCALING 0.25f

typedef __bf16 bf16x8 __attribute__((ext_vector_type(8)));
typedef float floatx4 __attribute__((ext_vector_type(4)));

static __device__ __forceinline__ unsigned short f32_to_bf16(float f) {
  unsigned int u = __float_as_uint(f);
  u += 0x7FFFu + ((u >> 16) & 1u);   // round-to-nearest-even
  return (unsigned short)(u >> 16);
}

// async global->LDS, 16B per lane. LDS dest is wave-uniform base + lane*16.
static __device__ __forceinline__ void async_ld16(const void* g, void* l) {
  __builtin_amdgcn_global_load_lds(
      (const __attribute__((address_space(1))) unsigned int*)g,
      (__attribute__((address_space(3))) unsigned int*)l, 16, 0, 0);
}

// ---------------- kernel 1: convert x fp32 -> bf16 ----------------
__global__ __launch_bounds__(256) void cvt_x_kernel(const float4* __restrict__ x,
                                                    ushort4* __restrict__ xb) {
  int i = blockIdx.x * 256 + threadIdx.x;   // grid sized exactly: no bounds check
  float4 v = x[i];
  ushort4 o;
  o.x = f32_to_bf16(v.x);
  o.y = f32_to_bf16(v.y);
  o.z = f32_to_bf16(v.z);
  o.w = f32_to_bf16(v.w);
  xb[i] = o;
}

// ---------------- kernel 2: W_eff = bf16(wq*scale + 0.25*B@A) ----------------
// R2: A-tile unpadded [64][64] so the r-loop reads it as an aligned float4
// (1 ds_read_b128 instead of 4 b32; 2-way aliasing is free). Bs stays padded
// for the column-broadcast reads.
__global__ __launch_bounds__(256) void build_weff_kernel(
    const int* __restrict__ wq, const float* __restrict__ scale_p,
    const float* __restrict__ A, const float* __restrict__ B,
    unsigned short* __restrict__ Weff) {
  __shared__ float Bs[64][65];                 // [o][r], padded
  __shared__ __align__(16) float As[64][64];   // [r][k], unpadded for float4

  const int tid = threadIdx.x;
  const int o0 = blockIdx.y * 64;
  const int k0 = blockIdx.x * 64;
  const float scale = scale_p[0];

  for (int i = tid; i < 64 * 64; i += 256) {
    int o = i >> 6, r = i & 63;
    Bs[o][r] = B[(size_t)(o0 + o) * RANK + r];
  }
  for (int i = tid; i < 64 * 64; i += 256) {
    int r = i >> 6, kk = i & 63;
    As[r][kk] = A[(size_t)r * K_TOT + k0 + kk];
  }
  __syncthreads();

  const int to = tid >> 4;   // 0..15 -> o sub-block (4 rows)
  const int tk = tid & 15;   // 0..15 -> k sub-block (4 contiguous cols)
  float acc[4][4] = {};
#pragma unroll 8
  for (int r = 0; r < RANK; ++r) {
    float bv[4];
#pragma unroll
    for (int a = 0; a < 4; ++a) bv[a] = Bs[to * 4 + a][r];
    floatx4 av = *(const floatx4*)&As[r][tk * 4];
#pragma unroll
    for (int a = 0; a < 4; ++a)
#pragma unroll
      for (int b = 0; b < 4; ++b) acc[a][b] += bv[a] * av[b];
  }
#pragma unroll
  for (int a = 0; a < 4; ++a) {
    const int o = o0 + to * 4 + a;
    const size_t base = (size_t)o * K_TOT + k0 + tk * 4;
    const int4 wv = *(const int4*)(wq + base);
    ushort4 st;
    st.x = f32_to_bf16((float)wv.x * scale + SCALING * acc[a][0]);
    st.y = f32_to_bf16((float)wv.y * scale + SCALING * acc[a][1]);
    st.z = f32_to_bf16((float)wv.z * scale + SCALING * acc[a][2]);
    st.w = f32_to_bf16((float)wv.w * scale + SCALING * acc[a][3]);
    *(ushort4*)(Weff + base) = st;
  }
}

// ---------------- kernel 3: main GEMM, out = Xb @ Weff^T ----------------
// R2 rewrite: 256x256 tile, BK=64, 8 waves (2M x 4N), 128 KiB double-buffered
// LDS, 4-phase-per-K-tile schedule with counted vmcnt(4) (never 0 in loop),
// XOR-swizzled LDS (write side via pre-swizzled global source; read side via
// the same XOR on ds_read addresses), setprio around MFMA clusters, XCD-aware
// block swizzle. One MFMA quadrant (16x mfma_f32_16x16x32_bf16) per phase.
//
// LDS layout (bytes): buf*65536 + {A:0, B:32768} + half*16384; a half is
// 128 rows x 64 bf16, row-major 128B rows, chunk' = chunk ^ (row&7) swizzle.
//
// Region ledger (group g computes tile g from buf b=g&1):
//   A halves of buf b   read  P1,P3(g); restaged (tile g+2) at P1,P2 of g+1
//   B halves of buf b   read  P1,P2(g); restaged (tile g+2) at P3,P4 of g
//   vmcnt(4) before the group-ending barrier leaves only the 4 newest stage
//   units (B of tile g+2) outstanding => tile g+1 fully resident for all waves.

template <int QM, int QN>
static __device__ __forceinline__ void ph_mfma(floatx4 (&acc)[8][4],
                                               const bf16x8 (&af)[4][2],
                                               const bf16x8 (&bf)[4][2]) {
#pragma unroll
  for (int ii = 0; ii < 4; ++ii)
#pragma unroll
    for (int jj = 0; jj < 2; ++jj) {
      floatx4 c = acc[QM * 4 + ii][QN * 2 + jj];
      c = __builtin_amdgcn_mfma_f32_16x16x32_bf16(af[ii][0], bf[QN * 2 + jj][0], c, 0, 0, 0);
      c = __builtin_amdgcn_mfma_f32_16x16x32_bf16(af[ii][1], bf[QN * 2 + jj][1], c, 0, 0, 0);
      acc[QM * 4 + ii][QN * 2 + jj] = c;
    }
}

__global__ __launch_bounds__(512, 2) void gemm_kernel(
    const unsigned short* __restrict__ Xb,   // [M_TOT][K_TOT] bf16 bits
    const unsigned short* __restrict__ Wb,   // [N_TOT][K_TOT] bf16 bits
    float* __restrict__ out) {               // [M_TOT][N_TOT] fp32
  __shared__ __align__(16) unsigned char smem[131072];

  const int tid = threadIdx.x;
  const int lane = tid & 63;
  const int wave = tid >> 6;   // 0..7
  const int wm = wave >> 2;    // 0..1 -> 128-row half
  const int wn = wave & 3;     // 0..3 -> 64-col quarter

  // XCD-aware swizzle: 512 blocks, 512 % 8 == 0 -> bijective
  const int bid = blockIdx.x;
  const int swz = (bid & 7) * 64 + (bid >> 3);
  const int bM = (swz >> 4) * 256;   // 32 M-blocks
  const int bN = (swz & 15) * 256;   // 16 N-blocks

  // staging source: thread covers 16B; row = tid>>3, chunk = (tid&7)^(row&7)
  const int srow = tid >> 3;                       // 0..63 rows per 8KB issue
  const int scol = ((tid & 7) ^ (srow & 7)) * 8;   // pre-swizzled k offset
  const unsigned short* xs = Xb + (size_t)(bM + srow) * K_TOT + scol;
  const unsigned short* ws = Wb + (size_t)(bN + srow) * K_TOT + scol;

  // ds_read addressing: frag row = (lane&15), logical chunk = ks*4+(lane>>4)
  const int rb = (lane & 15) * 128;
  const int c0 = (((lane >> 4) + 0) ^ (lane & 7)) * 16;
  const int c1 = (((lane >> 4) + 4) ^ (lane & 7)) * 16;
  const int aBase = wm * 16384;
  const int bBase = 32768 + (wn >> 1) * 16384 + (wn & 1) * 8192;

  floatx4 acc[8][4] = {};
  bf16x8 af[4][2], bf[4][2];

#define BAR() asm volatile("s_barrier" ::: "memory")
#define WAIT_LGKM0() asm volatile("s_waitcnt lgkmcnt(0)" ::: "memory")
#define WAIT_VM(N) asm volatile("s_waitcnt vmcnt(" #N ")" ::: "memory")
#define STAGE_A(BUF, H, S, KO)                                              \
  async_ld16(xs + (size_t)((H) * 128 + (S) * 64) * K_TOT + (KO),            \
             smem + (BUF) * 65536 + (H) * 16384 + (S) * 8192 + tid * 16)
#define STAGE_B(BUF, H, S, KO)                                              \
  async_ld16(ws + (size_t)((H) * 128 + (S) * 64) * K_TOT + (KO),            \
             smem + (BUF) * 65536 + 32768 + (H) * 16384 + (S) * 8192 + tid * 16)
#define DSR_A(BUF, QM, II, KS)                                              \
  af[II][KS] = *(const bf16x8*)(smem + (BUF) * 65536 + aBase +              \
                                ((QM) * 4 + (II)) * 2048 + rb + ((KS) ? c1 : c0))
#define DSR_B(BUF, J, KS)                                                   \
  bf[J][KS] = *(const bf16x8*)(smem + (BUF) * 65536 + bBase +               \
                               (J) * 2048 + rb + ((KS) ? c1 : c0))

#define GROUP(BUF, KA, KB)                                                  \
  {                                                                         \
    /* P1: read A qm=0 + B j=0,1; stage A-half0 of next tile -> buf^1 */    \
    DSR_A(BUF, 0, 0, 0); DSR_A(BUF, 0, 0, 1);                               \
    DSR_A(BUF, 0, 1, 0); DSR_A(BUF, 0, 1, 1);                               \
    DSR_A(BUF, 0, 2, 0); DSR_A(BUF, 0, 2, 1);                               \
    DSR_A(BUF, 0, 3, 0); DSR_A(BUF, 0, 3, 1);                               \
    DSR_B(BUF, 0, 0); DSR_B(BUF, 0, 1);                                     \
    DSR_B(BUF, 1, 0); DSR_B(BUF, 1, 1);                                     \
    STAGE_A((BUF) ^ 1, 0, 0, KA); STAGE_A((BUF) ^ 1, 0, 1, KA);             \
    BAR(); WAIT_LGKM0();                                                    \
    __builtin_amdgcn_s_setprio(1);                                          \
    ph_mfma<0, 0>(acc, af, bf);                                             \
    __builtin_amdgcn_s_setprio(0);                                          \
    BAR();                                                                  \
    /* P2: read B j=2,3; stage A-half1 of next tile -> buf^1 */             \
    DSR_B(BUF, 2, 0); DSR_B(BUF, 2, 1);                                     \
    DSR_B(BUF, 3, 0); DSR_B(BUF, 3, 1);                                     \
    STAGE_A((BUF) ^ 1, 1, 0, KA); STAGE_A((BUF) ^ 1, 1, 1, KA);             \
    BAR(); WAIT_LGKM0();                                                    \
    __builtin_amdgcn_s_setprio(1);                                          \
    ph_mfma<0, 1>(acc, af, bf);                                             \
    __builtin_amdgcn_s_setprio(0);                                          \
    BAR();                                                                  \
    /* P3: read A qm=1; stage B-half0 of tile+2 -> buf (B reads drained) */ \
    DSR_A(BUF, 1, 0, 0); DSR_A(BUF, 1, 0, 1);                               \
    DSR_A(BUF, 1, 1, 0); DSR_A(BUF, 1, 1, 1);                               \
    DSR_A(BUF, 1, 2, 0); DSR_A(BUF, 1, 2, 1);                               \
    DSR_A(BUF, 1, 3, 0); DSR_A(BUF, 1, 3, 1);                               \
    STAGE_B(BUF, 0, 0, KB); STAGE_B(BUF, 0, 1, KB);                         \
    BAR(); WAIT_LGKM0();                                                    \
    __builtin_amdgcn_s_setprio(1);                                          \
    ph_mfma<1, 1>(acc, af, bf);                                             \
    __builtin_amdgcn_s_setprio(0);                                          \
    BAR();                                                                  \
    /* P4: no reads; stage B-half1 of tile+2; counted vmcnt, NOT 0 */       \
    STAGE_B(BUF, 1, 0, KB); STAGE_B(BUF, 1, 1, KB);                         \
    BAR();                                                                  \
    __builtin_amdgcn_s_setprio(1);                                          \
    ph_mfma<1, 0>(acc, af, bf);                                             \
    __builtin_amdgcn_s_setprio(0);                                          \
    WAIT_VM(4);                                                             \
    BAR();                                                                  \
  }

  // prologue: tile0 (A+B) -> buf0, tile1 B-halves -> buf1; drain once.
  STAGE_A(0, 0, 0, 0); STAGE_A(0, 0, 1, 0);
  STAGE_A(0, 1, 0, 0); STAGE_A(0, 1, 1, 0);
  STAGE_B(0, 0, 0, 0); STAGE_B(0, 0, 1, 0);
  STAGE_B(0, 1, 0, 0); STAGE_B(0, 1, 1, 0);
  STAGE_B(1, 0, 0, 64); STAGE_B(1, 0, 1, 64);
  STAGE_B(1, 1, 0, 64); STAGE_B(1, 1, 1, 64);
  WAIT_VM(0);
  BAR();

  // 64 K-tiles, 2 per iteration (compile-time buffer indices). Stage targets
  // wrap with &63 (redundant but harmless — never read).
  for (int kt = 0; kt < 64; kt += 2) {
    const int ka0 = ((kt + 1) & 63) * 64;   // A of tile kt+1 -> buf1
    const int kb0 = ((kt + 2) & 63) * 64;   // B of tile kt+2 -> buf0
    const int ka1 = ((kt + 2) & 63) * 64;   // A of tile kt+2 -> buf0
    const int kb1 = ((kt + 3) & 63) * 64;   // B of tile kt+3 -> buf1
    GROUP(0, ka0, kb0);
    GROUP(1, ka1, kb1);
  }
  WAIT_VM(0);   // drain tail stages before workgroup exit

  // epilogue: C(i,j,r): row = bM+wm*128+i*16+(lane>>4)*4+r, col = bN+wn*64+j*16+(lane&15)
  const int row0 = bM + wm * 128 + ((lane >> 4) << 2);
  const int col0 = bN + wn * 64 + (lane & 15);
#pragma unroll
  for (int i = 0; i < 8; ++i) {
#pragma unroll
    for (int j = 0; j < 4; ++j) {
#pragma unroll
      for (int r = 0; r < 4; ++r) {
        out[(size_t)(row0 + i * 16 + r) * N_TOT + (col0 + j * 16)] = acc[i][j][r];
      }
    }
  }
#undef BAR
#undef WAIT_LGKM0
#undef WAIT_VM
#undef STAGE_A
#undef STAGE_B
#undef DSR_A
#undef DSR_B
#undef GROUP
}

extern "C" void kernel_launch(void* const* d_in, const int* in_sizes, int n_in,
                              void* d_out, int out_size, void* d_ws, size_t ws_size,
                              hipStream_t stream) {
  const float* x      = (const float*)d_in[0];   // [4,2048,4096] fp32
  const int*   wq     = (const int*)d_in[1];     // [4096,4096] int
  const float* wscale = (const float*)d_in[2];   // [1] fp32
  const float* lora_A = (const float*)d_in[3];   // [64,4096] fp32
  const float* lora_B = (const float*)d_in[4];   // [4096,64] fp32
  float* out = (float*)d_out;

  unsigned short* xb   = (unsigned short*)d_ws;
  unsigned short* weff = (unsigned short*)((char*)d_ws + (size_t)M_TOT * K_TOT * 2);

  cvt_x_kernel<<<32768, 256, 0, stream>>>((const float4*)x, (ushort4*)xb);
  build_weff_kernel<<<dim3(K_TOT / 64, N_TOT / 64), 256, 0, stream>>>(
      wq, wscale, lora_A, lora_B, weff);
  gemm_kernel<<<512, 512, 0, stream>>>(xb, weff, out);
}